// Round 5
// baseline (165.033 us; speedup 1.0000x reference)
//
#include <hip/hip_runtime.h>
#include <hip/hip_bf16.h>
#include <math.h>

// Problem constants
#define T_TOK   32768            // B*S tokens
#define EDIM    768
#define FDIM    3072
#define NQ      8

#define NET     24               // EDIM/32  (e-tiles)
#define NKF     192              // FDIM/16  (k-frags)
#define NFT     96               // FDIM/32  (f-tiles = exp steps)
#define NTT     1024             // T_TOK/32 (token-tiles)

// Main geometry: wave = 64 tok (2 tt) x 192 e (6 et); block = 4 waves stacked
// in M = 256 tok x 192 e. Grid = 128 mblk x 4 panels = 512 blocks.
// ONE wave per SIMD (acc 192 AGPR + ~130 VGPR): the wave self-overlaps VALU
// under the MFMA pipe's issue shadow via SGB interleave.
#define NMB     128
#define NPAN    4

// Workspace layout (bytes): fragment-packed bf16 operands.
//  W2P[et][kf][lane][8] : main B-frags, f-permutation baked in (et-major ->
//                         uniform base advance along kf + 32-bit lane voffset)
//  W1P[ft][lane][8]     : expansion A-frags (g=1 lanes zero = K pad)
//  ZP [tt][lane][8]     : expansion B-frags (g=1 lanes zero = K pad)
#define W2P_BYTES (NKF * NET * 64 * 8 * 2)   // 4,718,592
#define W1P_BYTES (NFT * 64 * 8 * 2)         // 98,304
#define ZP_BYTES  (NTT * 64 * 8 * 2)         // 1,048,576
#define W1P_OFFU  (W2P_BYTES / 2)            // ushort offsets
#define ZP_OFFU   ((W2P_BYTES + W1P_BYTES) / 2)
#define WS_NEED   ((size_t)(W2P_BYTES + W1P_BYTES + ZP_BYTES))

typedef float f32x16 __attribute__((ext_vector_type(16)));
typedef float f32x4  __attribute__((ext_vector_type(4)));
typedef short bf16x8 __attribute__((ext_vector_type(8)));

union FragU { uint4 u; bf16x8 v; };

static __device__ __forceinline__ unsigned pack2(float lo, float hi) {
    unsigned r;
    asm("v_cvt_pk_bf16_f32 %0, %1, %2" : "=v"(r) : "v"(lo), "v"(hi));
    return r;
}

static __device__ __forceinline__ unsigned short f2bf(float f) {
    unsigned int u = __float_as_uint(f);
    unsigned int r = (u + 0x7FFFu + ((u >> 16) & 1u)) >> 16;
    return (unsigned short)r;
}

// ---------------------------------------------------------------------------
// Prologue pack (unchanged — layout verified r2/r3/r4).
// blocks [0,1152)->W2P, [1152,1176)->W1P, [1176,1432)->ZP.
// ---------------------------------------------------------------------------
__global__ __launch_bounds__(256) void ffq_pack(
    const float* __restrict__ x, const float* __restrict__ theta,
    const float* __restrict__ W1, const float* __restrict__ W2,
    unsigned short* __restrict__ ws)
{
    const int bid = blockIdx.x;
    unsigned short* W2P = ws;
    unsigned short* W1P = ws + W1P_OFFU;
    unsigned short* ZP  = ws + ZP_OFFU;

    if (bid < 1152) {
        const int t = bid * 256 + threadIdx.x;
        const int lane = t & 63, fe = t >> 6;
        const int kf = fe / NET, et = fe - kf * NET;
        const int g = lane >> 5, c = lane & 31;
        const int e  = et * 32 + c;
        const int f0 = kf * 16 + g * 4;
        const float4 a = *(const float4*)(W2 + (size_t)e * FDIM + f0);
        const float4 b = *(const float4*)(W2 + (size_t)e * FDIM + f0 + 8);
        FragU u;
        u.u.x = pack2(a.x, a.y); u.u.y = pack2(a.z, a.w);
        u.u.z = pack2(b.x, b.y); u.u.w = pack2(b.z, b.w);
        *(uint4*)(W2P + (((size_t)et * NKF + kf) * 64 + lane) * 8) = u.u;
    } else if (bid < 1176) {
        const int t = (bid - 1152) * 256 + threadIdx.x;
        const int lane = t & 63, ft = t >> 6;
        const int g = lane >> 5, c = lane & 31;
        FragU u; u.u = (uint4){0, 0, 0, 0};
        if (g == 0) {
            const float4 a = *(const float4*)(W1 + (size_t)(ft * 32 + c) * NQ);
            const float4 b = *(const float4*)(W1 + (size_t)(ft * 32 + c) * NQ + 4);
            u.u.x = pack2(a.x, a.y); u.u.y = pack2(a.z, a.w);
            u.u.z = pack2(b.x, b.y); u.u.w = pack2(b.z, b.w);
        }
        *(uint4*)(W1P + (size_t)t * 8) = u.u;
    } else {
        const int t = (bid - 1176) * 256 + threadIdx.x;
        const int lane = t & 63, tt = t >> 6;
        const int g = lane >> 5, c = lane & 31;
        FragU u; u.u = (uint4){0, 0, 0, 0};
        if (g == 0) {
            const int token = tt * 32 + c;
            const float4 a = *(const float4*)(x + (size_t)token * EDIM);
            const float4 b = *(const float4*)(x + (size_t)token * EDIM + 4);
            const float z0 = __cosf(a.x) * __cosf(theta[0]);
            const float z1 = __cosf(a.y) * __cosf(theta[1]);
            const float z2 = __cosf(a.z) * __cosf(theta[2]);
            const float z3 = __cosf(a.w) * __cosf(theta[3]);
            const float z4 = __cosf(b.x) * __cosf(theta[4]);
            const float z5 = __cosf(b.y) * __cosf(theta[5]);
            const float z6 = __cosf(b.z) * __cosf(theta[6]);
            const float z7 = __cosf(b.w) * __cosf(theta[7]);
            u.u.x = pack2(z0, z1); u.u.y = pack2(z2, z3);
            u.u.z = pack2(z4, z5); u.u.w = pack2(z6, z7);
        }
        *(uint4*)(ZP + (size_t)t * 8) = u.u;
    }
}

// ---------------------------------------------------------------------------
// Main: LDS-free fused FFN, 1 fat wave per SIMD (2 tt x 6 et).
// Per ft-body: 2 exp MFMA + 24 main MFMA + 48 cvt VALU + 13 loads.
// ---------------------------------------------------------------------------
#define SGB(mask, n) __builtin_amdgcn_sched_group_barrier((mask), (n), 0)

__global__ __launch_bounds__(256, 1) void ffq_main(
    const unsigned short* __restrict__ ws, float* __restrict__ out)
{
    const unsigned short* W1Pp = ws + W1P_OFFU;
    const unsigned short* ZP   = ws + ZP_OFFU;

    const int tid  = threadIdx.x;
    const int wave = tid >> 6;
    const int lane = tid & 63;
    const int g    = lane >> 5;
    const int c    = lane & 31;

    // XCD swizzle: 512 = 8 x 64 (bijective).
    const int sw    = (blockIdx.x & 7) * 64 + (blockIdx.x >> 3);
    const int panel = sw / NMB;          // 0..3
    const int mblk  = sw % NMB;          // 0..127

    const int tt0 = mblk * 8 + wave * 2; // wave owns tt0, tt0+1
    const int et0 = panel * 6;           // wave spans et0..et0+5
    const size_t lo8 = (size_t)lane * 8;

    const bf16x8 zb0 = *(const bf16x8*)(ZP + (size_t)tt0 * 512 + lo8);
    const bf16x8 zb1 = *(const bf16x8*)(ZP + (size_t)(tt0 + 1) * 512 + lo8);

    // 32-bit per-lane voffsets into W2P; uniform base advances 2048 B/body.
    const unsigned lane16 = (unsigned)lane * 16u;
    const unsigned vo0 = (unsigned)((et0 + 0) * NKF) * 1024u + lane16;
    const unsigned vo1 = (unsigned)((et0 + 1) * NKF) * 1024u + lane16;
    const unsigned vo2 = (unsigned)((et0 + 2) * NKF) * 1024u + lane16;
    const unsigned vo3 = (unsigned)((et0 + 3) * NKF) * 1024u + lane16;
    const unsigned vo4 = (unsigned)((et0 + 4) * NKF) * 1024u + lane16;
    const unsigned vo5 = (unsigned)((et0 + 5) * NKF) * 1024u + lane16;
    const char* Wb = (const char*)ws;    // uniform W2P base (advanced in loop)

    const f32x16 Zc = (f32x16)(0.f);
    f32x16 A00 = Zc, A01 = Zc, A02 = Zc, A03 = Zc, A04 = Zc, A05 = Zc;
    f32x16 A10 = Zc, A11 = Zc, A12 = Zc, A13 = Zc, A14 = Zc, A15 = Zc;
    f32x16 d0, d1;
    bf16x8 a0l, a0h, a1l, a1h;
    bf16x8 Bl0, Bl1, Bl2, Bl3, Bl4, Bl5;
    bf16x8 Bh0, Bh1, Bh2, Bh3, Bh4, Bh5;
    bf16x8 wa;

#define MFMA32(A, B, C) __builtin_amdgcn_mfma_f32_32x32x16_bf16((A), (B), (C), 0, 0, 0)

// aF slot j = relu(D reg o+j): regs 0..7 -> lo kf, 8..15 -> hi kf (verified r2).
#define MKAF(d, o) ({                                                    \
        FragU u_;                                                        \
        u_.u.x = pack2(fmaxf((d)[(o)+0], 0.f), fmaxf((d)[(o)+1], 0.f));  \
        u_.u.y = pack2(fmaxf((d)[(o)+2], 0.f), fmaxf((d)[(o)+3], 0.f));  \
        u_.u.z = pack2(fmaxf((d)[(o)+4], 0.f), fmaxf((d)[(o)+5], 0.f));  \
        u_.u.w = pack2(fmaxf((d)[(o)+6], 0.f), fmaxf((d)[(o)+7], 0.f));  \
        u_.v; })

    // ---- Prologue: B-frags kf-pair 0, wa(0), exp(0), wa(1), cvt(0) ----
    Bl0 = *(const bf16x8*)(Wb + vo0);        Bh0 = *(const bf16x8*)(Wb + vo0 + 1024);
    Bl1 = *(const bf16x8*)(Wb + vo1);        Bh1 = *(const bf16x8*)(Wb + vo1 + 1024);
    Bl2 = *(const bf16x8*)(Wb + vo2);        Bh2 = *(const bf16x8*)(Wb + vo2 + 1024);
    Bl3 = *(const bf16x8*)(Wb + vo3);        Bh3 = *(const bf16x8*)(Wb + vo3 + 1024);
    Bl4 = *(const bf16x8*)(Wb + vo4);        Bh4 = *(const bf16x8*)(Wb + vo4 + 1024);
    Bl5 = *(const bf16x8*)(Wb + vo5);        Bh5 = *(const bf16x8*)(Wb + vo5 + 1024);
    wa  = *(const bf16x8*)(W1Pp + lo8);
    d0 = MFMA32(wa, zb0, Zc);
    d1 = MFMA32(wa, zb1, Zc);
    wa  = *(const bf16x8*)(W1Pp + 512 + lo8);
    a0l = MKAF(d0, 0); a0h = MKAF(d0, 8);
    a1l = MKAF(d1, 0); a1h = MKAF(d1, 8);

    #pragma unroll 1
    for (int n = 0; n < NFT; ++n) {
        // exp for ft n+1; wa then reloads for ft n+2
        d0 = MFMA32(wa, zb0, Zc);
        d1 = MFMA32(wa, zb1, Zc);
        wa = *(const bf16x8*)(W1Pp + (size_t)(n + 2) * 512 + lo8);

        // lo phase: 12 mains on kf-lo, then refill Bl (kf-pair n+1), cvt-lo
        A00 = MFMA32(a0l, Bl0, A00); A01 = MFMA32(a0l, Bl1, A01);
        A02 = MFMA32(a0l, Bl2, A02); A03 = MFMA32(a0l, Bl3, A03);
        A04 = MFMA32(a0l, Bl4, A04); A05 = MFMA32(a0l, Bl5, A05);
        A10 = MFMA32(a1l, Bl0, A10); A11 = MFMA32(a1l, Bl1, A11);
        A12 = MFMA32(a1l, Bl2, A12); A13 = MFMA32(a1l, Bl3, A13);
        A14 = MFMA32(a1l, Bl4, A14); A15 = MFMA32(a1l, Bl5, A15);
        Bl0 = *(const bf16x8*)(Wb + vo0 + 2048);
        Bl1 = *(const bf16x8*)(Wb + vo1 + 2048);
        Bl2 = *(const bf16x8*)(Wb + vo2 + 2048);
        Bl3 = *(const bf16x8*)(Wb + vo3 + 2048);
        Bl4 = *(const bf16x8*)(Wb + vo4 + 2048);
        Bl5 = *(const bf16x8*)(Wb + vo5 + 2048);
        a0l = MKAF(d0, 0);
        a1l = MKAF(d1, 0);
        // schedule template, lo region: exp(2) + 6x{main 2, valu 4}
        SGB(0x8, 2);
        SGB(0x8, 2); SGB(0x2, 4);
        SGB(0x8, 2); SGB(0x2, 4);
        SGB(0x8, 2); SGB(0x2, 4);
        SGB(0x8, 2); SGB(0x2, 4);
        SGB(0x8, 2); SGB(0x2, 4);
        SGB(0x8, 2); SGB(0x2, 4);

        // hi phase: 12 mains on kf-hi, refill Bh, cvt-hi
        A00 = MFMA32(a0h, Bh0, A00); A01 = MFMA32(a0h, Bh1, A01);
        A02 = MFMA32(a0h, Bh2, A02); A03 = MFMA32(a0h, Bh3, A03);
        A04 = MFMA32(a0h, Bh4, A04); A05 = MFMA32(a0h, Bh5, A05);
        A10 = MFMA32(a1h, Bh0, A10); A11 = MFMA32(a1h, Bh1, A11);
        A12 = MFMA32(a1h, Bh2, A12); A13 = MFMA32(a1h, Bh3, A13);
        A14 = MFMA32(a1h, Bh4, A14); A15 = MFMA32(a1h, Bh5, A15);
        Bh0 = *(const bf16x8*)(Wb + vo0 + 3072);
        Bh1 = *(const bf16x8*)(Wb + vo1 + 3072);
        Bh2 = *(const bf16x8*)(Wb + vo2 + 3072);
        Bh3 = *(const bf16x8*)(Wb + vo3 + 3072);
        Bh4 = *(const bf16x8*)(Wb + vo4 + 3072);
        Bh5 = *(const bf16x8*)(Wb + vo5 + 3072);
        a0h = MKAF(d0, 8);
        a1h = MKAF(d1, 8);
        SGB(0x8, 2); SGB(0x2, 4);
        SGB(0x8, 2); SGB(0x2, 4);
        SGB(0x8, 2); SGB(0x2, 4);
        SGB(0x8, 2); SGB(0x2, 4);
        SGB(0x8, 2); SGB(0x2, 4);
        SGB(0x8, 2); SGB(0x2, 4);

        Wb += 2048;
    }

    // ---- Epilogue: D row(token%32) = (r&3)+8*(r>>2)+4g, col(e%32) = c ----
#define STORE_ACC(ACC, T, E) do {                                              \
        const size_t rb = (size_t)((tt0 + (T)) * 32 + 4 * g) * EDIM            \
                          + (size_t)(et0 + (E)) * 32 + c;                      \
        _Pragma("unroll")                                                      \
        for (int r = 0; r < 16; ++r)                                           \
            out[rb + (size_t)((r & 3) + 8 * (r >> 2)) * EDIM] = ACC[r];        \
    } while (0)

    STORE_ACC(A00, 0, 0); STORE_ACC(A01, 0, 1); STORE_ACC(A02, 0, 2);
    STORE_ACC(A03, 0, 3); STORE_ACC(A04, 0, 4); STORE_ACC(A05, 0, 5);
    STORE_ACC(A10, 1, 0); STORE_ACC(A11, 1, 1); STORE_ACC(A12, 1, 2);
    STORE_ACC(A13, 1, 3); STORE_ACC(A14, 1, 4); STORE_ACC(A15, 1, 5);

#undef MFMA32
#undef MKAF
#undef STORE_ACC
}

// ---------------------------------------------------------------------------
// Fallback (round-1 kernel) if ws is too small. Known-correct, 455 us.
// ---------------------------------------------------------------------------
#define BM      128
#define NPANEL  6
#define NMBLK   256
#define BK      64
#define NKSTEP  (FDIM / BK)
#define HA_ST   72
#define BT_ST   72

__global__ __launch_bounds__(256) void ffq_fused(
    const float* __restrict__ x, const float* __restrict__ theta,
    const float* __restrict__ W1, const float* __restrict__ W2,
    float* __restrict__ out)
{
    __shared__ __align__(16) unsigned short hA[BM * HA_ST];
    __shared__ __align__(16) unsigned short Bt[BM * BT_ST];

    const int tid  = threadIdx.x;
    const int wave = tid >> 6;
    const int lane = tid & 63;
    const int l15  = lane & 15;
    const int lhi  = lane >> 4;
    const int wm   = wave >> 1;
    const int wn   = wave & 1;

    const int panel = blockIdx.x / NMBLK;
    const int mblk  = blockIdx.x % NMBLK;
    const int t0 = mblk * BM;
    const int n0 = panel * BM;

    bf16x8 zf[2];
    #pragma unroll
    for (int s = 0; s < 2; ++s) {
        bf16x8 z = {0, 0, 0, 0, 0, 0, 0, 0};
        if (lhi == 0) {
            const int tok = t0 + (wave * 2 + s) * 16 + l15;
            const float4* xp = (const float4*)(x + (size_t)tok * EDIM);
            const float4 x0 = xp[0];
            const float4 x1 = xp[1];
            z[0] = (short)f2bf(cosf(x0.x) * cosf(theta[0]));
            z[1] = (short)f2bf(cosf(x0.y) * cosf(theta[1]));
            z[2] = (short)f2bf(cosf(x0.z) * cosf(theta[2]));
            z[3] = (short)f2bf(cosf(x0.w) * cosf(theta[3]));
            z[4] = (short)f2bf(cosf(x1.x) * cosf(theta[4]));
            z[5] = (short)f2bf(cosf(x1.y) * cosf(theta[5]));
            z[6] = (short)f2bf(cosf(x1.z) * cosf(theta[6]));
            z[7] = (short)f2bf(cosf(x1.w) * cosf(theta[7]));
        }
        zf[s] = z;
    }

    f32x4 acc[4][4];
    #pragma unroll
    for (int mi = 0; mi < 4; ++mi)
        #pragma unroll
        for (int ni = 0; ni < 4; ++ni)
            acc[mi][ni] = (f32x4){0.f, 0.f, 0.f, 0.f};

    for (int ks = 0; ks < NKSTEP; ++ks) {
        const int k0 = ks * BK;
        __syncthreads();
        {
            const int e    = tid >> 1;
            const int half = (tid & 1) * 32;
            const float* src = W2 + (size_t)(n0 + e) * FDIM + k0 + half;
            unsigned short* dst = &Bt[e * BT_ST + half];
            #pragma unroll
            for (int i = 0; i < 4; ++i) {
                const float4 a = ((const float4*)src)[2 * i];
                const float4 b = ((const float4*)src)[2 * i + 1];
                bf16x8 v;
                v[0] = (short)f2bf(a.x); v[1] = (short)f2bf(a.y);
                v[2] = (short)f2bf(a.z); v[3] = (short)f2bf(a.w);
                v[4] = (short)f2bf(b.x); v[5] = (short)f2bf(b.y);
                v[6] = (short)f2bf(b.z); v[7] = (short)f2bf(b.w);
                *(bf16x8*)(dst + i * 8) = v;
            }
        }
        #pragma unroll
        for (int ns = 0; ns < 4; ++ns) {
            bf16x8 wf = {0, 0, 0, 0, 0, 0, 0, 0};
            if (lhi == 0) {
                const float* wp = W1 + (size_t)(k0 + ns * 16 + l15) * NQ;
                const float4 a = ((const float4*)wp)[0];
                const float4 b = ((const float4*)wp)[1];
                wf[0] = (short)f2bf(a.x); wf[1] = (short)f2bf(a.y);
                wf[2] = (short)f2bf(a.z); wf[3] = (short)f2bf(a.w);
                wf[4] = (short)f2bf(b.x); wf[5] = (short)f2bf(b.y);
                wf[6] = (short)f2bf(b.z); wf[7] = (short)f2bf(b.w);
            }
            #pragma unroll
            for (int s = 0; s < 2; ++s) {
                f32x4 hd = __builtin_amdgcn_mfma_f32_16x16x32_bf16(
                    zf[s], wf, (f32x4){0.f, 0.f, 0.f, 0.f}, 0, 0, 0);
                const int row = (wave * 2 + s) * 16 + lhi * 4;
                const int col = ns * 16 + l15;
                #pragma unroll
                for (int j = 0; j < 4; ++j) {
                    const float v = hd[j] > 0.f ? hd[j] : 0.f;
                    hA[(row + j) * HA_ST + col] = f2bf(v);
                }
            }
        }
        __syncthreads();
        #pragma unroll
        for (int ksub = 0; ksub < 2; ++ksub) {
            bf16x8 af[4], bg[4];
            #pragma unroll
            for (int mi = 0; mi < 4; ++mi) {
                const int row = wm * 64 + mi * 16 + l15;
                af[mi] = *(const bf16x8*)&hA[row * HA_ST + ksub * 32 + lhi * 8];
            }
            #pragma unroll
            for (int ni = 0; ni < 4; ++ni) {
                const int e = wn * 64 + ni * 16 + l15;
                bg[ni] = *(const bf16x8*)&Bt[e * BT_ST + ksub * 32 + lhi * 8];
            }
            #pragma unroll
            for (int mi = 0; mi < 4; ++mi)
                #pragma unroll
                for (int ni = 0; ni < 4; ++ni)
                    acc[mi][ni] = __builtin_amdgcn_mfma_f32_16x16x32_bf16(
                        af[mi], bg[ni], acc[mi][ni], 0, 0, 0);
        }
    }

    #pragma unroll
    for (int mi = 0; mi < 4; ++mi) {
        const int rbase = t0 + wm * 64 + mi * 16 + lhi * 4;
        #pragma unroll
        for (int ni = 0; ni < 4; ++ni) {
            const int cc = n0 + wn * 64 + ni * 16 + l15;
            #pragma unroll
            for (int j = 0; j < 4; ++j)
                out[(size_t)(rbase + j) * EDIM + cc] = acc[mi][ni][j];
        }
    }
}

extern "C" void kernel_launch(void* const* d_in, const int* in_sizes, int n_in,
                              void* d_out, int out_size, void* d_ws, size_t ws_size,
                              hipStream_t stream) {
    const float* x     = (const float*)d_in[0];
    const float* theta = (const float*)d_in[1];
    const float* W1    = (const float*)d_in[2];
    const float* W2    = (const float*)d_in[3];
    float* out = (float*)d_out;

    if (ws_size >= WS_NEED) {
        ffq_pack<<<dim3(1432), dim3(256), 0, stream>>>(x, theta, W1, W2,
                                                       (unsigned short*)d_ws);
        ffq_main<<<dim3(NPAN * NMB), dim3(256), 0, stream>>>(
            (const unsigned short*)d_ws, out);
    } else {
        ffq_fused<<<dim3(NPANEL * NMBLK), dim3(256), 0, stream>>>(x, theta, W1, W2, out);
    }
}

// Round 7
// 156.994 us; speedup vs baseline: 1.0512x; 1.0512x over previous
//
#include <hip/hip_runtime.h>
#include <hip/hip_bf16.h>
#include <math.h>

// Problem constants
#define T_TOK   32768            // B*S tokens
#define EDIM    768
#define FDIM    3072
#define NQ      8

#define NET     24               // EDIM/32  (e-tiles)
#define NKF     192              // FDIM/16  (k-frags)
#define NFT     96               // FDIM/32  (f-tiles = exp steps)
#define NTT     1024             // T_TOK/32 (token-tiles)

// Main geometry (round-4 proven best): wave = 64 tok (2 tt) x 128 e (4 et);
// block = 4 waves stacked in M = 256 tok x 128 e. Grid = 128 x 6 = 768.
// 2 waves/SIMD (acc 128 AGPR + ~120 VGPR).
#define NMB     128
#define NPAN    6

// Workspace layout (bytes): fragment-packed bf16 operands.
//  W2P[et][kf][lane][8] : main B-frags, f-permutation baked in
//  W1P[ft][lane][8]     : expansion A-frags (g=1 lanes zero = K pad)
//  ZP [tt][lane][8]     : expansion B-frags (g=1 lanes zero = K pad)
#define W2P_BYTES (NKF * NET * 64 * 8 * 2)   // 4,718,592
#define W1P_BYTES (NFT * 64 * 8 * 2)         // 98,304
#define ZP_BYTES  (NTT * 64 * 8 * 2)         // 1,048,576
#define W1P_OFFU  (W2P_BYTES / 2)            // ushort offsets
#define ZP_OFFU   ((W2P_BYTES + W1P_BYTES) / 2)
#define WS_NEED   ((size_t)(W2P_BYTES + W1P_BYTES + ZP_BYTES))

typedef float f32x16 __attribute__((ext_vector_type(16)));
typedef float f32x4  __attribute__((ext_vector_type(4)));
typedef short bf16x8 __attribute__((ext_vector_type(8)));

union FragU { uint4 u; bf16x8 v; };

static __device__ __forceinline__ unsigned pack2(float lo, float hi) {
    unsigned r;
    asm("v_cvt_pk_bf16_f32 %0, %1, %2" : "=v"(r) : "v"(lo), "v"(hi));
    return r;
}

static __device__ __forceinline__ unsigned short f2bf(float f) {
    unsigned int u = __float_as_uint(f);
    unsigned int r = (u + 0x7FFFu + ((u >> 16) & 1u)) >> 16;
    return (unsigned short)r;
}

// ---------------------------------------------------------------------------
// Prologue pack (unchanged — layout verified r2-r5).
// blocks [0,1152)->W2P, [1152,1176)->W1P, [1176,1432)->ZP.
// ---------------------------------------------------------------------------
__global__ __launch_bounds__(256) void ffq_pack(
    const float* __restrict__ x, const float* __restrict__ theta,
    const float* __restrict__ W1, const float* __restrict__ W2,
    unsigned short* __restrict__ ws)
{
    const int bid = blockIdx.x;
    unsigned short* W2P = ws;
    unsigned short* W1P = ws + W1P_OFFU;
    unsigned short* ZP  = ws + ZP_OFFU;

    if (bid < 1152) {
        const int t = bid * 256 + threadIdx.x;
        const int lane = t & 63, fe = t >> 6;
        const int kf = fe / NET, et = fe - kf * NET;
        const int g = lane >> 5, c = lane & 31;
        const int e  = et * 32 + c;
        const int f0 = kf * 16 + g * 4;
        const float4 a = *(const float4*)(W2 + (size_t)e * FDIM + f0);
        const float4 b = *(const float4*)(W2 + (size_t)e * FDIM + f0 + 8);
        FragU u;
        u.u.x = pack2(a.x, a.y); u.u.y = pack2(a.z, a.w);
        u.u.z = pack2(b.x, b.y); u.u.w = pack2(b.z, b.w);
        *(uint4*)(W2P + (((size_t)et * NKF + kf) * 64 + lane) * 8) = u.u;
    } else if (bid < 1176) {
        const int t = (bid - 1152) * 256 + threadIdx.x;
        const int lane = t & 63, ft = t >> 6;
        const int g = lane >> 5, c = lane & 31;
        FragU u; u.u = (uint4){0, 0, 0, 0};
        if (g == 0) {
            const float4 a = *(const float4*)(W1 + (size_t)(ft * 32 + c) * NQ);
            const float4 b = *(const float4*)(W1 + (size_t)(ft * 32 + c) * NQ + 4);
            u.u.x = pack2(a.x, a.y); u.u.y = pack2(a.z, a.w);
            u.u.z = pack2(b.x, b.y); u.u.w = pack2(b.z, b.w);
        }
        *(uint4*)(W1P + (size_t)t * 8) = u.u;
    } else {
        const int t = (bid - 1176) * 256 + threadIdx.x;
        const int lane = t & 63, tt = t >> 6;
        const int g = lane >> 5, c = lane & 31;
        FragU u; u.u = (uint4){0, 0, 0, 0};
        if (g == 0) {
            const int token = tt * 32 + c;
            const float4 a = *(const float4*)(x + (size_t)token * EDIM);
            const float4 b = *(const float4*)(x + (size_t)token * EDIM + 4);
            const float z0 = __cosf(a.x) * __cosf(theta[0]);
            const float z1 = __cosf(a.y) * __cosf(theta[1]);
            const float z2 = __cosf(a.z) * __cosf(theta[2]);
            const float z3 = __cosf(a.w) * __cosf(theta[3]);
            const float z4 = __cosf(b.x) * __cosf(theta[4]);
            const float z5 = __cosf(b.y) * __cosf(theta[5]);
            const float z6 = __cosf(b.z) * __cosf(theta[6]);
            const float z7 = __cosf(b.w) * __cosf(theta[7]);
            u.u.x = pack2(z0, z1); u.u.y = pack2(z2, z3);
            u.u.z = pack2(z4, z5); u.u.w = pack2(z6, z7);
        }
        *(uint4*)(ZP + (size_t)t * 8) = u.u;
    }
}

// ---------------------------------------------------------------------------
// Main: LDS-free fused FFN, wave = 2 tt x 4 et, 2 waves/SIMD (r4 structure).
// Per iter: 2 exp MFMA + 16 main MFMA + 48 cvt VALU + 9 VMEM loads.
// r7 change vs r4: SGB template gains VMEM_READ(0x20) slots so loads issue
// ~1 iteration (~580 cyc) before consumption instead of sinking to uses.
// ---------------------------------------------------------------------------
#define SGB(mask, n) __builtin_amdgcn_sched_group_barrier((mask), (n), 0)

__global__ __launch_bounds__(256, 2) void ffq_main(
    const unsigned short* __restrict__ ws, float* __restrict__ out)
{
    const unsigned short* W1Pp = ws + W1P_OFFU;
    const unsigned short* ZP   = ws + ZP_OFFU;

    const int tid  = threadIdx.x;
    const int wave = tid >> 6;
    const int lane = tid & 63;
    const int g    = lane >> 5;
    const int c    = lane & 31;

    // XCD swizzle: 768 = 8 x 96 (bijective).
    const int sw    = (blockIdx.x & 7) * 96 + (blockIdx.x >> 3);
    const int panel = sw / NMB;          // 0..5
    const int mblk  = sw % NMB;          // 0..127

    const int tt0 = mblk * 8 + wave * 2; // wave owns tt0, tt0+1
    const int et0 = panel * 4;           // wave spans et0..et0+3
    const size_t lo8 = (size_t)lane * 8;

    const bf16x8 zb0 = *(const bf16x8*)(ZP + (size_t)tt0 * 512 + lo8);
    const bf16x8 zb1 = *(const bf16x8*)(ZP + (size_t)(tt0 + 1) * 512 + lo8);

    // 32-bit per-lane voffsets into W2P; uniform base advances 2048 B/iter.
    const unsigned lane16 = (unsigned)lane * 16u;
    const unsigned vo0 = (unsigned)((et0 + 0) * NKF) * 1024u + lane16;
    const unsigned vo1 = (unsigned)((et0 + 1) * NKF) * 1024u + lane16;
    const unsigned vo2 = (unsigned)((et0 + 2) * NKF) * 1024u + lane16;
    const unsigned vo3 = (unsigned)((et0 + 3) * NKF) * 1024u + lane16;
    const char* Wb = (const char*)ws;    // uniform W2P base (advanced in loop)

    const f32x16 Zc = (f32x16)(0.f);
    f32x16 A00 = Zc, A01 = Zc, A02 = Zc, A03 = Zc;
    f32x16 A10 = Zc, A11 = Zc, A12 = Zc, A13 = Zc;
    f32x16 d0, d1;
    bf16x8 a0l, a0h, a1l, a1h;
    bf16x8 Bl0, Bl1, Bl2, Bl3, Bh0, Bh1, Bh2, Bh3;
    bf16x8 wa;

#define MFMA32(A, B, C) __builtin_amdgcn_mfma_f32_32x32x16_bf16((A), (B), (C), 0, 0, 0)

// aF slot j = relu(D reg o+j): regs 0..7 -> lo kf, 8..15 -> hi kf (verified r2).
#define MKAF(d, o) ({                                                    \
        FragU u_;                                                        \
        u_.u.x = pack2(fmaxf((d)[(o)+0], 0.f), fmaxf((d)[(o)+1], 0.f));  \
        u_.u.y = pack2(fmaxf((d)[(o)+2], 0.f), fmaxf((d)[(o)+3], 0.f));  \
        u_.u.z = pack2(fmaxf((d)[(o)+4], 0.f), fmaxf((d)[(o)+5], 0.f));  \
        u_.u.w = pack2(fmaxf((d)[(o)+6], 0.f), fmaxf((d)[(o)+7], 0.f));  \
        u_.v; })

    // ---- Prologue: B-frags kf-pair 0, wa(0), exp(0), wa(1), cvt(0) ----
    Bl0 = *(const bf16x8*)(Wb + vo0);        Bh0 = *(const bf16x8*)(Wb + vo0 + 1024);
    Bl1 = *(const bf16x8*)(Wb + vo1);        Bh1 = *(const bf16x8*)(Wb + vo1 + 1024);
    Bl2 = *(const bf16x8*)(Wb + vo2);        Bh2 = *(const bf16x8*)(Wb + vo2 + 1024);
    Bl3 = *(const bf16x8*)(Wb + vo3);        Bh3 = *(const bf16x8*)(Wb + vo3 + 1024);
    wa  = *(const bf16x8*)(W1Pp + lo8);
    d0 = MFMA32(wa, zb0, Zc);
    d1 = MFMA32(wa, zb1, Zc);
    wa  = *(const bf16x8*)(W1Pp + 512 + lo8);
    a0l = MKAF(d0, 0); a0h = MKAF(d0, 8);
    a1l = MKAF(d1, 0); a1h = MKAF(d1, 8);

    #pragma unroll 1
    for (int n = 0; n < NFT; ++n) {
        // exp for ft n+1; wa then reloads for ft n+2
        d0 = MFMA32(wa, zb0, Zc);
        d1 = MFMA32(wa, zb1, Zc);
        wa = *(const bf16x8*)(W1Pp + (size_t)(n + 2) * 512 + lo8);

        // lo phase: 8 mains on kf-lo, then refill Bl (kf-pair n+1), cvt-lo
        A00 = MFMA32(a0l, Bl0, A00); A01 = MFMA32(a0l, Bl1, A01);
        A02 = MFMA32(a0l, Bl2, A02); A03 = MFMA32(a0l, Bl3, A03);
        A10 = MFMA32(a1l, Bl0, A10); A11 = MFMA32(a1l, Bl1, A11);
        A12 = MFMA32(a1l, Bl2, A12); A13 = MFMA32(a1l, Bl3, A13);
        Bl0 = *(const bf16x8*)(Wb + vo0 + 2048);
        Bl1 = *(const bf16x8*)(Wb + vo1 + 2048);
        Bl2 = *(const bf16x8*)(Wb + vo2 + 2048);
        Bl3 = *(const bf16x8*)(Wb + vo3 + 2048);
        a0l = MKAF(d0, 0);
        a1l = MKAF(d1, 0);
        // schedule, lo region: exp(2)+wa-load, then 4x{main 2, load 1, cvt 6}
        SGB(0x8, 2); SGB(0x20, 1);
        SGB(0x8, 2); SGB(0x20, 1); SGB(0x2, 6);
        SGB(0x8, 2); SGB(0x20, 1); SGB(0x2, 6);
        SGB(0x8, 2); SGB(0x20, 1); SGB(0x2, 6);
        SGB(0x8, 2); SGB(0x20, 1); SGB(0x2, 6);

        // hi phase: 8 mains on kf-hi, refill Bh, cvt-hi
        A00 = MFMA32(a0h, Bh0, A00); A01 = MFMA32(a0h, Bh1, A01);
        A02 = MFMA32(a0h, Bh2, A02); A03 = MFMA32(a0h, Bh3, A03);
        A10 = MFMA32(a1h, Bh0, A10); A11 = MFMA32(a1h, Bh1, A11);
        A12 = MFMA32(a1h, Bh2, A12); A13 = MFMA32(a1h, Bh3, A13);
        Bh0 = *(const bf16x8*)(Wb + vo0 + 3072);
        Bh1 = *(const bf16x8*)(Wb + vo1 + 3072);
        Bh2 = *(const bf16x8*)(Wb + vo2 + 3072);
        Bh3 = *(const bf16x8*)(Wb + vo3 + 3072);
        a0h = MKAF(d0, 8);
        a1h = MKAF(d1, 8);
        SGB(0x8, 2); SGB(0x20, 1); SGB(0x2, 6);
        SGB(0x8, 2); SGB(0x20, 1); SGB(0x2, 6);
        SGB(0x8, 2); SGB(0x20, 1); SGB(0x2, 6);
        SGB(0x8, 2); SGB(0x20, 1); SGB(0x2, 6);

        Wb += 2048;
    }

    // ---- Epilogue: D row(token%32) = (r&3)+8*(r>>2)+4g, col(e%32) = c ----
#define STORE_ACC(ACC, T, E) do {                                              \
        const size_t rb = (size_t)((tt0 + (T)) * 32 + 4 * g) * EDIM            \
                          + (size_t)(et0 + (E)) * 32 + c;                      \
        _Pragma("unroll")                                                      \
        for (int r = 0; r < 16; ++r)                                           \
            out[rb + (size_t)((r & 3) + 8 * (r >> 2)) * EDIM] = ACC[r];        \
    } while (0)

    STORE_ACC(A00, 0, 0); STORE_ACC(A01, 0, 1); STORE_ACC(A02, 0, 2); STORE_ACC(A03, 0, 3);
    STORE_ACC(A10, 1, 0); STORE_ACC(A11, 1, 1); STORE_ACC(A12, 1, 2); STORE_ACC(A13, 1, 3);

#undef MFMA32
#undef MKAF
#undef STORE_ACC
}

// ---------------------------------------------------------------------------
// Fallback (round-1 kernel) if ws is too small. Known-correct, 455 us.
// ---------------------------------------------------------------------------
#define BM      128
#define NPANEL  6
#define NMBLK   256
#define BK      64
#define NKSTEP  (FDIM / BK)
#define HA_ST   72
#define BT_ST   72

__global__ __launch_bounds__(256) void ffq_fused(
    const float* __restrict__ x, const float* __restrict__ theta,
    const float* __restrict__ W1, const float* __restrict__ W2,
    float* __restrict__ out)
{
    __shared__ __align__(16) unsigned short hA[BM * HA_ST];
    __shared__ __align__(16) unsigned short Bt[BM * BT_ST];

    const int tid  = threadIdx.x;
    const int wave = tid >> 6;
    const int lane = tid & 63;
    const int l15  = lane & 15;
    const int lhi  = lane >> 4;
    const int wm   = wave >> 1;
    const int wn   = wave & 1;

    const int panel = blockIdx.x / NMBLK;
    const int mblk  = blockIdx.x % NMBLK;
    const int t0 = mblk * BM;
    const int n0 = panel * BM;

    bf16x8 zf[2];
    #pragma unroll
    for (int s = 0; s < 2; ++s) {
        bf16x8 z = {0, 0, 0, 0, 0, 0, 0, 0};
        if (lhi == 0) {
            const int tok = t0 + (wave * 2 + s) * 16 + l15;
            const float4* xp = (const float4*)(x + (size_t)tok * EDIM);
            const float4 x0 = xp[0];
            const float4 x1 = xp[1];
            z[0] = (short)f2bf(cosf(x0.x) * cosf(theta[0]));
            z[1] = (short)f2bf(cosf(x0.y) * cosf(theta[1]));
            z[2] = (short)f2bf(cosf(x0.z) * cosf(theta[2]));
            z[3] = (short)f2bf(cosf(x0.w) * cosf(theta[3]));
            z[4] = (short)f2bf(cosf(x1.x) * cosf(theta[4]));
            z[5] = (short)f2bf(cosf(x1.y) * cosf(theta[5]));
            z[6] = (short)f2bf(cosf(x1.z) * cosf(theta[6]));
            z[7] = (short)f2bf(cosf(x1.w) * cosf(theta[7]));
        }
        zf[s] = z;
    }

    f32x4 acc[4][4];
    #pragma unroll
    for (int mi = 0; mi < 4; ++mi)
        #pragma unroll
        for (int ni = 0; ni < 4; ++ni)
            acc[mi][ni] = (f32x4){0.f, 0.f, 0.f, 0.f};

    for (int ks = 0; ks < NKSTEP; ++ks) {
        const int k0 = ks * BK;
        __syncthreads();
        {
            const int e    = tid >> 1;
            const int half = (tid & 1) * 32;
            const float* src = W2 + (size_t)(n0 + e) * FDIM + k0 + half;
            unsigned short* dst = &Bt[e * BT_ST + half];
            #pragma unroll
            for (int i = 0; i < 4; ++i) {
                const float4 a = ((const float4*)src)[2 * i];
                const float4 b = ((const float4*)src)[2 * i + 1];
                bf16x8 v;
                v[0] = (short)f2bf(a.x); v[1] = (short)f2bf(a.y);
                v[2] = (short)f2bf(a.z); v[3] = (short)f2bf(a.w);
                v[4] = (short)f2bf(b.x); v[5] = (short)f2bf(b.y);
                v[6] = (short)f2bf(b.z); v[7] = (short)f2bf(b.w);
                *(bf16x8*)(dst + i * 8) = v;
            }
        }
        #pragma unroll
        for (int ns = 0; ns < 4; ++ns) {
            bf16x8 wf = {0, 0, 0, 0, 0, 0, 0, 0};
            if (lhi == 0) {
                const float* wp = W1 + (size_t)(k0 + ns * 16 + l15) * NQ;
                const float4 a = ((const float4*)wp)[0];
                const float4 b = ((const float4*)wp)[1];
                wf[0] = (short)f2bf(a.x); wf[1] = (short)f2bf(a.y);
                wf[2] = (short)f2bf(a.z); wf[3] = (short)f2bf(a.w);
                wf[4] = (short)f2bf(b.x); wf[5] = (short)f2bf(b.y);
                wf[6] = (short)f2bf(b.z); wf[7] = (short)f2bf(b.w);
            }
            #pragma unroll
            for (int s = 0; s < 2; ++s) {
                f32x4 hd = __builtin_amdgcn_mfma_f32_16x16x32_bf16(
                    zf[s], wf, (f32x4){0.f, 0.f, 0.f, 0.f}, 0, 0, 0);
                const int row = (wave * 2 + s) * 16 + lhi * 4;
                const int col = ns * 16 + l15;
                #pragma unroll
                for (int j = 0; j < 4; ++j) {
                    const float v = hd[j] > 0.f ? hd[j] : 0.f;
                    hA[(row + j) * HA_ST + col] = f2bf(v);
                }
            }
        }
        __syncthreads();
        #pragma unroll
        for (int ksub = 0; ksub < 2; ++ksub) {
            bf16x8 af[4], bg[4];
            #pragma unroll
            for (int mi = 0; mi < 4; ++mi) {
                const int row = wm * 64 + mi * 16 + l15;
                af[mi] = *(const bf16x8*)&hA[row * HA_ST + ksub * 32 + lhi * 8];
            }
            #pragma unroll
            for (int ni = 0; ni < 4; ++ni) {
                const int e = wn * 64 + ni * 16 + l15;
                bg[ni] = *(const bf16x8*)&Bt[e * BT_ST + ksub * 32 + lhi * 8];
            }
            #pragma unroll
            for (int mi = 0; mi < 4; ++mi)
                #pragma unroll
                for (int ni = 0; ni < 4; ++ni)
                    acc[mi][ni] = __builtin_amdgcn_mfma_f32_16x16x32_bf16(
                        af[mi], bg[ni], acc[mi][ni], 0, 0, 0);
        }
    }

    #pragma unroll
    for (int mi = 0; mi < 4; ++mi) {
        const int rbase = t0 + wm * 64 + mi * 16 + lhi * 4;
        #pragma unroll
        for (int ni = 0; ni < 4; ++ni) {
            const int cc = n0 + wn * 64 + ni * 16 + l15;
            #pragma unroll
            for (int j = 0; j < 4; ++j)
                out[(size_t)(rbase + j) * EDIM + cc] = acc[mi][ni][j];
        }
    }
}

extern "C" void kernel_launch(void* const* d_in, const int* in_sizes, int n_in,
                              void* d_out, int out_size, void* d_ws, size_t ws_size,
                              hipStream_t stream) {
    const float* x     = (const float*)d_in[0];
    const float* theta = (const float*)d_in[1];
    const float* W1    = (const float*)d_in[2];
    const float* W2    = (const float*)d_in[3];
    float* out = (float*)d_out;

    if (ws_size >= WS_NEED) {
        ffq_pack<<<dim3(1432), dim3(256), 0, stream>>>(x, theta, W1, W2,
                                                       (unsigned short*)d_ws);
        ffq_main<<<dim3(NPAN * NMB), dim3(256), 0, stream>>>(
            (const unsigned short*)d_ws, out);
    } else {
        ffq_fused<<<dim3(NPANEL * NMBLK), dim3(256), 0, stream>>>(x, theta, W1, W2, out);
    }
}

// Round 9
// 156.139 us; speedup vs baseline: 1.0570x; 1.0055x over previous
//
#include <hip/hip_runtime.h>
#include <hip/hip_bf16.h>
#include <math.h>

// Problem constants
#define T_TOK   32768            // B*S tokens
#define EDIM    768
#define FDIM    3072
#define NQ      8

#define NET     24               // EDIM/32  (e-tiles)
#define NKF     192              // FDIM/16  (k-frags)
#define NFT     96               // FDIM/32  (f-tiles = exp steps)
#define NTT     1024             // T_TOK/32 (token-tiles)

// Main geometry (r4 tiling): wave = 64 tok (2 tt) x 128 e (4 et); block =
// 4 waves stacked in M = 256 tok x 128 e. Grid = 128 x 6 = 768.
// r8/r9: B-frags + wa staged ONCE per block in LDS via global_load_lds
// (4x VMEM cut), double-buffered, one barrier/iter.
// r9 fix: explicit vmcnt(0) fence before EVERY __syncthreads -- cross-wave
// visibility of the DMA must not rely on the compiler's implicit drain.
#define NMB     128
#define NPAN    6

// Workspace layout (bytes): fragment-packed bf16 operands.
//  W2P[et][kf][lane][8] : main B-frags, f-permutation baked in
//  W1P[ft][lane][8]     : expansion A-frags (g=1 lanes zero = K pad)
//  ZP [tt][lane][8]     : expansion B-frags (g=1 lanes zero = K pad)
#define W2P_BYTES (NKF * NET * 64 * 8 * 2)   // 4,718,592
#define W1P_BYTES (NFT * 64 * 8 * 2)         // 98,304
#define ZP_BYTES  (NTT * 64 * 8 * 2)         // 1,048,576
#define W1P_OFFU  (W2P_BYTES / 2)            // ushort offsets
#define ZP_OFFU   ((W2P_BYTES + W1P_BYTES) / 2)
#define WS_NEED   ((size_t)(W2P_BYTES + W1P_BYTES + ZP_BYTES))

typedef float f32x16 __attribute__((ext_vector_type(16)));
typedef float f32x4  __attribute__((ext_vector_type(4)));
typedef short bf16x8 __attribute__((ext_vector_type(8)));

union FragU { uint4 u; bf16x8 v; };

static __device__ __forceinline__ unsigned pack2(float lo, float hi) {
    unsigned r;
    asm("v_cvt_pk_bf16_f32 %0, %1, %2" : "=v"(r) : "v"(lo), "v"(hi));
    return r;
}

static __device__ __forceinline__ unsigned short f2bf(float f) {
    unsigned int u = __float_as_uint(f);
    unsigned int r = (u + 0x7FFFu + ((u >> 16) & 1u)) >> 16;
    return (unsigned short)r;
}

// ---------------------------------------------------------------------------
// Prologue pack (unchanged — layout verified r2-r7).
// blocks [0,1152)->W2P, [1152,1176)->W1P, [1176,1432)->ZP.
// ---------------------------------------------------------------------------
__global__ __launch_bounds__(256) void ffq_pack(
    const float* __restrict__ x, const float* __restrict__ theta,
    const float* __restrict__ W1, const float* __restrict__ W2,
    unsigned short* __restrict__ ws)
{
    const int bid = blockIdx.x;
    unsigned short* W2P = ws;
    unsigned short* W1P = ws + W1P_OFFU;
    unsigned short* ZP  = ws + ZP_OFFU;

    if (bid < 1152) {
        const int t = bid * 256 + threadIdx.x;
        const int lane = t & 63, fe = t >> 6;
        const int kf = fe / NET, et = fe - kf * NET;
        const int g = lane >> 5, c = lane & 31;
        const int e  = et * 32 + c;
        const int f0 = kf * 16 + g * 4;
        const float4 a = *(const float4*)(W2 + (size_t)e * FDIM + f0);
        const float4 b = *(const float4*)(W2 + (size_t)e * FDIM + f0 + 8);
        FragU u;
        u.u.x = pack2(a.x, a.y); u.u.y = pack2(a.z, a.w);
        u.u.z = pack2(b.x, b.y); u.u.w = pack2(b.z, b.w);
        *(uint4*)(W2P + (((size_t)et * NKF + kf) * 64 + lane) * 8) = u.u;
    } else if (bid < 1176) {
        const int t = (bid - 1152) * 256 + threadIdx.x;
        const int lane = t & 63, ft = t >> 6;
        const int g = lane >> 5, c = lane & 31;
        FragU u; u.u = (uint4){0, 0, 0, 0};
        if (g == 0) {
            const float4 a = *(const float4*)(W1 + (size_t)(ft * 32 + c) * NQ);
            const float4 b = *(const float4*)(W1 + (size_t)(ft * 32 + c) * NQ + 4);
            u.u.x = pack2(a.x, a.y); u.u.y = pack2(a.z, a.w);
            u.u.z = pack2(b.x, b.y); u.u.w = pack2(b.z, b.w);
        }
        *(uint4*)(W1P + (size_t)t * 8) = u.u;
    } else {
        const int t = (bid - 1176) * 256 + threadIdx.x;
        const int lane = t & 63, tt = t >> 6;
        const int g = lane >> 5, c = lane & 31;
        FragU u; u.u = (uint4){0, 0, 0, 0};
        if (g == 0) {
            const int token = tt * 32 + c;
            const float4 a = *(const float4*)(x + (size_t)token * EDIM);
            const float4 b = *(const float4*)(x + (size_t)token * EDIM + 4);
            const float z0 = __cosf(a.x) * __cosf(theta[0]);
            const float z1 = __cosf(a.y) * __cosf(theta[1]);
            const float z2 = __cosf(a.z) * __cosf(theta[2]);
            const float z3 = __cosf(a.w) * __cosf(theta[3]);
            const float z4 = __cosf(b.x) * __cosf(theta[4]);
            const float z5 = __cosf(b.y) * __cosf(theta[5]);
            const float z6 = __cosf(b.z) * __cosf(theta[6]);
            const float z7 = __cosf(b.w) * __cosf(theta[7]);
            u.u.x = pack2(z0, z1); u.u.y = pack2(z2, z3);
            u.u.z = pack2(z4, z5); u.u.w = pack2(z6, z7);
        }
        *(uint4*)(ZP + (size_t)t * 8) = u.u;
    }
}

// ---------------------------------------------------------------------------
// Main: fused FFN, B+wa LDS-staged per block (global_load_lds, dbuf).
// Per iter per wave: 9 ds_read_b128, 2 exp + 16 main MFMA, 48 cvt, 2-3 DMA.
// ---------------------------------------------------------------------------
#define SGB(mask, n) __builtin_amdgcn_sched_group_barrier((mask), (n), 0)

// Explicit DMA drain + scheduling fence, then barrier (rule #18: the asm
// waitcnt needs a sched_barrier so nothing is hoisted across it).
#define SYNC_WITH_DMA_DRAIN() do {                                  \
        asm volatile("s_waitcnt vmcnt(0)" ::: "memory");            \
        __builtin_amdgcn_sched_barrier(0);                          \
        __syncthreads();                                            \
    } while (0)

#define GLL(gsrc, ldst)                                                        \
    __builtin_amdgcn_global_load_lds(                                          \
        (const __attribute__((address_space(1))) unsigned int*)(const void*)(gsrc), \
        (__attribute__((address_space(3))) unsigned int*)(void*)(ldst), 16, 0, 0)

__global__ __launch_bounds__(256, 2) void ffq_main(
    const unsigned short* __restrict__ ws, float* __restrict__ out)
{
    __shared__ __align__(16) unsigned short Bst[2][9][512];   // 18 KB

    const int tid  = threadIdx.x;
    const int wave = tid >> 6;
    const int lane = tid & 63;
    const int g    = lane >> 5;
    const int c    = lane & 31;

    // XCD swizzle: 768 = 8 x 96 (bijective).
    const int sw    = (blockIdx.x & 7) * 96 + (blockIdx.x >> 3);
    const int panel = sw / NMB;          // 0..5
    const int mblk  = sw % NMB;          // 0..127

    const int tt0 = mblk * 8 + wave * 2; // wave owns tt0, tt0+1
    const int et0 = panel * 4;           // block spans et0..et0+3
    const size_t lo8 = (size_t)lane * 8;
    const unsigned lane16 = (unsigned)lane * 16u;

    const unsigned short* ZP = ws + ZP_OFFU;
    const bf16x8 zb0 = *(const bf16x8*)(ZP + (size_t)tt0 * 512 + lo8);
    const bf16x8 zb1 = *(const bf16x8*)(ZP + (size_t)(tt0 + 1) * 512 + lo8);

    // Per-lane source offsets into W2P (bytes); uniform base advances 2048/iter.
    const unsigned vo0 = (unsigned)((et0 + 0) * NKF) * 1024u + lane16;
    const unsigned vo1 = (unsigned)((et0 + 1) * NKF) * 1024u + lane16;
    const unsigned vo2 = (unsigned)((et0 + 2) * NKF) * 1024u + lane16;
    const unsigned vo3 = (unsigned)((et0 + 3) * NKF) * 1024u + lane16;
    const char* W2base = (const char*)ws;
    const char* W1s = (const char*)ws + W2P_BYTES + lane16;   // per-lane W1P src

    char* l0 = (char*)&Bst[0][0][0];
    char* l1 = (char*)&Bst[1][0][0];
    const unsigned short* r0 = &Bst[0][0][0] + lo8;
    const unsigned short* r1 = &Bst[1][0][0] + lo8;

    const f32x16 Zc = (f32x16)(0.f);
    f32x16 A00 = Zc, A01 = Zc, A02 = Zc, A03 = Zc;
    f32x16 A10 = Zc, A11 = Zc, A12 = Zc, A13 = Zc;
    f32x16 d0, d1;
    bf16x8 a0l, a0h, a1l, a1h;

#define MFMA32(A, B, C) __builtin_amdgcn_mfma_f32_32x32x16_bf16((A), (B), (C), 0, 0, 0)

// aF slot j = relu(D reg o+j): regs 0..7 -> lo kf, 8..15 -> hi kf (verified r2).
#define MKAF(d, o) ({                                                    \
        FragU u_;                                                        \
        u_.u.x = pack2(fmaxf((d)[(o)+0], 0.f), fmaxf((d)[(o)+1], 0.f));  \
        u_.u.y = pack2(fmaxf((d)[(o)+2], 0.f), fmaxf((d)[(o)+3], 0.f));  \
        u_.u.z = pack2(fmaxf((d)[(o)+4], 0.f), fmaxf((d)[(o)+5], 0.f));  \
        u_.u.w = pack2(fmaxf((d)[(o)+6], 0.f), fmaxf((d)[(o)+7], 0.f));  \
        u_.v; })

    // ---- Prologue ----
    // Stage set for iter 0 into buf0: B kf-pair 0 (+0/+1024) and W1P[1].
    if (wave == 0) {
        GLL(W2base + vo0,        l0 + 0);
        GLL(W2base + vo0 + 1024, l0 + 4096);
        GLL(W1s + 1024,          l0 + 8192);
    } else if (wave == 1) {
        GLL(W2base + vo1,        l0 + 1024);
        GLL(W2base + vo1 + 1024, l0 + 5120);
    } else if (wave == 2) {
        GLL(W2base + vo2,        l0 + 2048);
        GLL(W2base + vo2 + 1024, l0 + 6144);
    } else {
        GLL(W2base + vo3,        l0 + 3072);
        GLL(W2base + vo3 + 1024, l0 + 7168);
    }
    // Direct wa for ft0; exp(ft0) + cvt -> a*(ft0).
    {
        const bf16x8 wa0 = *(const bf16x8*)(W1s);   // W1P[0] frag, per-lane
        d0 = MFMA32(wa0, zb0, Zc);
        d1 = MFMA32(wa0, zb1, Zc);
        a0l = MKAF(d0, 0); a0h = MKAF(d0, 8);
        a1l = MKAF(d1, 0); a1h = MKAF(d1, 8);
    }

    int wslot = 2048;   // body n stages W1P[n+2]

// One iter: drain+barrier; stage next set into LN; ds_read current from RB;
// exp (ft n+1); 16 mains (ft n); cvt -> a*(ft n+1).
#define BODY(RB, LN) do {                                                      \
        SYNC_WITH_DMA_DRAIN();                                                 \
        if (wave == 0) {                                                       \
            GLL(W2base + vo0 + 2048, (LN) + 0);                                \
            GLL(W2base + vo0 + 3072, (LN) + 4096);                             \
            GLL(W1s + wslot,         (LN) + 8192);                             \
        } else if (wave == 1) {                                                \
            GLL(W2base + vo1 + 2048, (LN) + 1024);                             \
            GLL(W2base + vo1 + 3072, (LN) + 5120);                             \
        } else if (wave == 2) {                                                \
            GLL(W2base + vo2 + 2048, (LN) + 2048);                             \
            GLL(W2base + vo2 + 3072, (LN) + 6144);                             \
        } else {                                                               \
            GLL(W2base + vo3 + 2048, (LN) + 3072);                             \
            GLL(W2base + vo3 + 3072, (LN) + 7168);                             \
        }                                                                      \
        wslot += 1024;                                                         \
        const bf16x8 wal = *(const bf16x8*)((RB) + 4096);                      \
        const bf16x8 Bl0 = *(const bf16x8*)((RB) + 0);                         \
        const bf16x8 Bl1 = *(const bf16x8*)((RB) + 512);                       \
        const bf16x8 Bl2 = *(const bf16x8*)((RB) + 1024);                      \
        const bf16x8 Bl3 = *(const bf16x8*)((RB) + 1536);                      \
        const bf16x8 Bh0 = *(const bf16x8*)((RB) + 2048);                      \
        const bf16x8 Bh1 = *(const bf16x8*)((RB) + 2560);                      \
        const bf16x8 Bh2 = *(const bf16x8*)((RB) + 3072);                      \
        const bf16x8 Bh3 = *(const bf16x8*)((RB) + 3584);                      \
        d0 = MFMA32(wal, zb0, Zc);                                             \
        d1 = MFMA32(wal, zb1, Zc);                                             \
        A00 = MFMA32(a0l, Bl0, A00); A01 = MFMA32(a0l, Bl1, A01);              \
        A02 = MFMA32(a0l, Bl2, A02); A03 = MFMA32(a0l, Bl3, A03);              \
        A10 = MFMA32(a1l, Bl0, A10); A11 = MFMA32(a1l, Bl1, A11);              \
        A12 = MFMA32(a1l, Bl2, A12); A13 = MFMA32(a1l, Bl3, A13);              \
        A00 = MFMA32(a0h, Bh0, A00); A01 = MFMA32(a0h, Bh1, A01);              \
        A02 = MFMA32(a0h, Bh2, A02); A03 = MFMA32(a0h, Bh3, A03);              \
        A10 = MFMA32(a1h, Bh0, A10); A11 = MFMA32(a1h, Bh1, A11);              \
        A12 = MFMA32(a1h, Bh2, A12); A13 = MFMA32(a1h, Bh3, A13);              \
        a0l = MKAF(d0, 0);  a1l = MKAF(d1, 0);                                 \
        a0h = MKAF(d0, 8);  a1h = MKAF(d1, 8);                                 \
        SGB(0x100, 5);                  /* wa + Bl reads first   */            \
        SGB(0x8, 2);                    /* exp                   */            \
        SGB(0x100, 4);                  /* Bh reads              */            \
        SGB(0x8, 2); SGB(0x2, 6);                                              \
        SGB(0x8, 2); SGB(0x2, 6);                                              \
        SGB(0x8, 2); SGB(0x2, 6);                                              \
        SGB(0x8, 2); SGB(0x2, 6);                                              \
        SGB(0x8, 2); SGB(0x2, 6);                                              \
        SGB(0x8, 2); SGB(0x2, 6);                                              \
        SGB(0x8, 2); SGB(0x2, 6);                                              \
        SGB(0x8, 2); SGB(0x2, 6);                                              \
        W2base += 2048;                                                        \
    } while (0)

    #pragma unroll 1
    for (int h = 0; h < NFT / 2; ++h) {
        BODY(r0, l1);
        BODY(r1, l0);
    }
    SYNC_WITH_DMA_DRAIN();   // drain in-flight DMA before LDS dealloc / epilogue

    // ---- Epilogue: D row(token%32) = (r&3)+8*(r>>2)+4g, col(e%32) = c ----
#define STORE_ACC(ACC, T, E) do {                                              \
        const size_t rb = (size_t)((tt0 + (T)) * 32 + 4 * g) * EDIM            \
                          + (size_t)(et0 + (E)) * 32 + c;                      \
        _Pragma("unroll")                                                      \
        for (int r = 0; r < 16; ++r)                                           \
            out[rb + (size_t)((r & 3) + 8 * (r >> 2)) * EDIM] = ACC[r];        \
    } while (0)

    STORE_ACC(A00, 0, 0); STORE_ACC(A01, 0, 1); STORE_ACC(A02, 0, 2); STORE_ACC(A03, 0, 3);
    STORE_ACC(A10, 1, 0); STORE_ACC(A11, 1, 1); STORE_ACC(A12, 1, 2); STORE_ACC(A13, 1, 3);

#undef MFMA32
#undef MKAF
#undef BODY
#undef STORE_ACC
}

// ---------------------------------------------------------------------------
// Fallback (round-1 kernel) if ws is too small. Known-correct, 455 us.
// ---------------------------------------------------------------------------
#define BM      128
#define NPANEL  6
#define NMBLK   256
#define BK      64
#define NKSTEP  (FDIM / BK)
#define HA_ST   72
#define BT_ST   72

__global__ __launch_bounds__(256) void ffq_fused(
    const float* __restrict__ x, const float* __restrict__ theta,
    const float* __restrict__ W1, const float* __restrict__ W2,
    float* __restrict__ out)
{
    __shared__ __align__(16) unsigned short hA[BM * HA_ST];
    __shared__ __align__(16) unsigned short Bt[BM * BT_ST];

    const int tid  = threadIdx.x;
    const int wave = tid >> 6;
    const int lane = tid & 63;
    const int l15  = lane & 15;
    const int lhi  = lane >> 4;
    const int wm   = wave >> 1;
    const int wn   = wave & 1;

    const int panel = blockIdx.x / NMBLK;
    const int mblk  = blockIdx.x % NMBLK;
    const int t0 = mblk * BM;
    const int n0 = panel * BM;

    bf16x8 zf[2];
    #pragma unroll
    for (int s = 0; s < 2; ++s) {
        bf16x8 z = {0, 0, 0, 0, 0, 0, 0, 0};
        if (lhi == 0) {
            const int tok = t0 + (wave * 2 + s) * 16 + l15;
            const float4* xp = (const float4*)(x + (size_t)tok * EDIM);
            const float4 x0 = xp[0];
            const float4 x1 = xp[1];
            z[0] = (short)f2bf(cosf(x0.x) * cosf(theta[0]));
            z[1] = (short)f2bf(cosf(x0.y) * cosf(theta[1]));
            z[2] = (short)f2bf(cosf(x0.z) * cosf(theta[2]));
            z[3] = (short)f2bf(cosf(x0.w) * cosf(theta[3]));
            z[4] = (short)f2bf(cosf(x1.x) * cosf(theta[4]));
            z[5] = (short)f2bf(cosf(x1.y) * cosf(theta[5]));
            z[6] = (short)f2bf(cosf(x1.z) * cosf(theta[6]));
            z[7] = (short)f2bf(cosf(x1.w) * cosf(theta[7]));
        }
        zf[s] = z;
    }

    f32x4 acc[4][4];
    #pragma unroll
    for (int mi = 0; mi < 4; ++mi)
        #pragma unroll
        for (int ni = 0; ni < 4; ++ni)
            acc[mi][ni] = (f32x4){0.f, 0.f, 0.f, 0.f};

    for (int ks = 0; ks < NKSTEP; ++ks) {
        const int k0 = ks * BK;
        __syncthreads();
        {
            const int e    = tid >> 1;
            const int half = (tid & 1) * 32;
            const float* src = W2 + (size_t)(n0 + e) * FDIM + k0 + half;
            unsigned short* dst = &Bt[e * BT_ST + half];
            #pragma unroll
            for (int i = 0; i < 4; ++i) {
                const float4 a = ((const float4*)src)[2 * i];
                const float4 b = ((const float4*)src)[2 * i + 1];
                bf16x8 v;
                v[0] = (short)f2bf(a.x); v[1] = (short)f2bf(a.y);
                v[2] = (short)f2bf(a.z); v[3] = (short)f2bf(a.w);
                v[4] = (short)f2bf(b.x); v[5] = (short)f2bf(b.y);
                v[6] = (short)f2bf(b.z); v[7] = (short)f2bf(b.w);
                *(bf16x8*)(dst + i * 8) = v;
            }
        }
        #pragma unroll
        for (int ns = 0; ns < 4; ++ns) {
            bf16x8 wf = {0, 0, 0, 0, 0, 0, 0, 0};
            if (lhi == 0) {
                const float* wp = W1 + (size_t)(k0 + ns * 16 + l15) * NQ;
                const float4 a = ((const float4*)wp)[0];
                const float4 b = ((const float4*)wp)[1];
                wf[0] = (short)f2bf(a.x); wf[1] = (short)f2bf(a.y);
                wf[2] = (short)f2bf(a.z); wf[3] = (short)f2bf(a.w);
                wf[4] = (short)f2bf(b.x); wf[5] = (short)f2bf(b.y);
                wf[6] = (short)f2bf(b.z); wf[7] = (short)f2bf(b.w);
            }
            #pragma unroll
            for (int s = 0; s < 2; ++s) {
                f32x4 hd = __builtin_amdgcn_mfma_f32_16x16x32_bf16(
                    zf[s], wf, (f32x4){0.f, 0.f, 0.f, 0.f}, 0, 0, 0);
                const int row = (wave * 2 + s) * 16 + lhi * 4;
                const int col = ns * 16 + l15;
                #pragma unroll
                for (int j = 0; j < 4; ++j) {
                    const float v = hd[j] > 0.f ? hd[j] : 0.f;
                    hA[(row + j) * HA_ST + col] = f2bf(v);
                }
            }
        }
        __syncthreads();
        #pragma unroll
        for (int ksub = 0; ksub < 2; ++ksub) {
            bf16x8 af[4], bg[4];
            #pragma unroll
            for (int mi = 0; mi < 4; ++mi) {
                const int row = wm * 64 + mi * 16 + l15;
                af[mi] = *(const bf16x8*)&hA[row * HA_ST + ksub * 32 + lhi * 8];
            }
            #pragma unroll
            for (int ni = 0; ni < 4; ++ni) {
                const int e = wn * 64 + ni * 16 + l15;
                bg[ni] = *(const bf16x8*)&Bt[e * BT_ST + ksub * 32 + lhi * 8];
            }
            #pragma unroll
            for (int mi = 0; mi < 4; ++mi)
                #pragma unroll
                for (int ni = 0; ni < 4; ++ni)
                    acc[mi][ni] = __builtin_amdgcn_mfma_f32_16x16x32_bf16(
                        af[mi], bg[ni], acc[mi][ni], 0, 0, 0);
        }
    }

    #pragma unroll
    for (int mi = 0; mi < 4; ++mi) {
        const int rbase = t0 + wm * 64 + mi * 16 + lhi * 4;
        #pragma unroll
        for (int ni = 0; ni < 4; ++ni) {
            const int cc = n0 + wn * 64 + ni * 16 + l15;
            #pragma unroll
            for (int j = 0; j < 4; ++j)
                out[(size_t)(rbase + j) * EDIM + cc] = acc[mi][ni][j];
        }
    }
}

extern "C" void kernel_launch(void* const* d_in, const int* in_sizes, int n_in,
                              void* d_out, int out_size, void* d_ws, size_t ws_size,
                              hipStream_t stream) {
    const float* x     = (const float*)d_in[0];
    const float* theta = (const float*)d_in[1];
    const float* W1    = (const float*)d_in[2];
    const float* W2    = (const float*)d_in[3];
    float* out = (float*)d_out;

    if (ws_size >= WS_NEED) {
        ffq_pack<<<dim3(1432), dim3(256), 0, stream>>>(x, theta, W1, W2,
                                                       (unsigned short*)d_ws);
        ffq_main<<<dim3(NPAN * NMB), dim3(256), 0, stream>>>(
            (const unsigned short*)d_ws, out);
    } else {
        ffq_fused<<<dim3(NPANEL * NMBLK), dim3(256), 0, stream>>>(x, theta, W1, W2, out);
    }
}